// Round 13
// baseline (1181.945 us; speedup 1.0000x reference)
//
#include <hip/hip_runtime.h>
#include <hip/hip_fp16.h>

#define NS   16384
#define NIN  16384
#define CIN  128
#define COUT 128
#define KNB  9
#define MCH  66              // 64 MLP channels + 1 (b3 ones) + 1 zero pad
#define QDIM (CIN*MCH)       // 8448, q = m*128 + j (j-fastest)
#define W0C  30.0f

typedef __bf16 bf16;
typedef bf16  bf16x8  __attribute__((ext_vector_type(8)));
typedef _Float16 f16;
typedef unsigned short u16;
typedef u16   u16x8   __attribute__((ext_vector_type(8)));
typedef float floatx4 __attribute__((ext_vector_type(4)));
typedef unsigned int u32;

__device__ inline u16 f2bf(float f){
  u32 u = __float_as_uint(f);
  u += 0x7fffu + ((u >> 16) & 1u);   // round-to-nearest-even
  return (u16)(u >> 16);
}
__device__ inline float bf2f(u16 s){
  return __uint_as_float((u32)s << 16);
}
__device__ inline u16 f2h(float f){
  f16 h = (f16)f; return __builtin_bit_cast(u16, h);
}
// 1-instr packed f32->2xbf16 (RNE), gfx950-verified instruction
__device__ inline u32 cvtpk2(float lo, float hi){
  u32 r; asm("v_cvt_pk_bf16_f32 %0, %1, %2" : "=v"(r) : "v"(lo), "v"(hi)); return r;
}

// X-format (build operands xT, hK) = f16; build uses __hfma2 (r12-verified).
#define F2X(f)  f2h(f)
#define X_ONE   0x3C00u

// barrier that orders LDS only — does NOT drain vmcnt (verified form)
#define WG_BARRIER() do { \
  asm volatile("s_waitcnt lgkmcnt(0)" ::: "memory"); \
  __builtin_amdgcn_s_barrier(); \
} while (0)

// ---------------- K_prep: grid-partitioned fusion of k1h | k_tr | k0_vt ----------
// (verbatim r12 — verified)
#define PREP_K1H  (NS/32)                 // 512
#define PREP_KTR  2048                    // 8192 tiles / 4 per block
#define PREP_K0   ((COUT*QDIM + 1023)/1024)  // 1056
__global__ __launch_bounds__(1024) void k_prep(
      const float* __restrict__ coords,
      const float* __restrict__ W1, const float* __restrict__ b1,
      const float* __restrict__ W2, const float* __restrict__ b2,
      const float* __restrict__ x,
      const float* __restrict__ W3, const float* __restrict__ b3,
      u32* __restrict__ hK, u16* __restrict__ xT, u16* __restrict__ Vt){
  __shared__ u16 sh[KNB][32][66];              // 38,016 B (k1h role)
  __shared__ __align__(16) float tfl[4][32][33]; // 16,896 B (k_tr role)
  const int bid = blockIdx.x;
  const int tid = threadIdx.x;

  if (bid < PREP_K1H){
    // ---------------- k1h role ----------------
    const int lane = tid & 63;
    const int w    = tid >> 6;         // 0..15
    const int l0   = bid*32;
    for (int e = w; e < KNB*32; e += 16){
      int k = e >> 5, l = e & 31;
      int pt = (k << 14) + l0 + l;
      float c0 = coords[2*pt], c1 = coords[2*pt+1];
      float z  = fmaf(c0, W1[lane], fmaf(c1, W1[64+lane], b1[lane]));
      float h1 = sinf(W0C * z);
      float acc = b2[lane];
      #pragma unroll
      for (int mp = 0; mp < 64; ++mp)
        acc = fmaf(__shfl(h1, mp, 64), W2[mp*64 + lane], acc);
      sh[k][l][lane] = F2X(sinf(acc));
      if (lane == 0){ sh[k][l][64] = X_ONE; sh[k][l][65] = 0; }  // 1.0, 0.0
    }
    __syncthreads();
    for (int e = tid; e < 66*5*32; e += 1024){
      int m  = e / 160;
      int r  = e - m*160;
      int kp = r >> 5;
      int l  = r & 31;
      u32 lo = sh[2*kp][l][m];
      u32 hi = (kp < 4) ? (u32)sh[2*kp+1][l][m] : 0u;
      hK[(((size_t)m*5 + kp) << 14) + l0 + l] = lo | (hi << 16);
    }
  } else if (bid < PREP_K1H + PREP_KTR){
    // ---------------- k_tr role: 4 tiles of 32x32 per block ----------------
    const int sub = tid >> 8;          // 0..3 : which tile
    const int tx  = tid & 31;
    const int ty  = (tid >> 5) & 7;
    const int t   = (bid - PREP_K1H)*4 + sub;   // 0..8191
    const int p0  = (t & 511) * 32;             // NIN/32 = 512
    const int j0  = ((t >> 9) & 3) * 32;        // CIN/32 = 4
    const int b   = t >> 11;                    // 4
    const float* xb  = x  + (size_t)b*CIN*NIN;
    u16*         xTb = xT + (size_t)b*NIN*CIN;
    #pragma unroll
    for (int n = 0; n < 4; ++n)
      tfl[sub][ty+8*n][tx] = xb[(size_t)(j0+ty+8*n)*NIN + p0+tx];
    __syncthreads();
    #pragma unroll
    for (int n = 0; n < 4; ++n)
      xTb[(size_t)(p0+ty+8*n)*CIN + j0+tx] = F2X(tfl[sub][tx][ty+8*n]);
  } else {
    // ---------------- k0_vt role (bf16 — feeds MFMA B directly) ----------------
    int idx = (bid - PREP_K1H - PREP_KTR)*1024 + tid;
    if (idx < COUT*QDIM){
      int i = idx / QDIM;
      int q = idx - i*QDIM;
      int m = q >> 7;
      int j = q & 127;
      float v = 0.f;
      if (m < 64)       v = W3[m*16384 + i*128 + j];
      else if (m == 64) v = b3[i*128 + j];
      Vt[idx] = f2bf(v);
    }
  }
}

// ---------------- K_fused: in-register A fragments (no A LDS round-trip) --------
// block: 32 rows (one b) x 128 i, 512 threads (8 waves), (512,4).
// Wave w = (rf = w>>2, kt = w&3). Thread (w,lane): builds A-row rf*16+(lane&15),
// j-chunk kt*4+(lane>>4) — a bijection with the old (lq,jc) builder — so its
// a2[s][8] IS the MFMA A-fragment for (rf,kt,slab s): lane holds
// A[row=lane&15][k-chunk=lane>>4] of the 16x32 tile. A never touches LDS:
// no A writes/reads/conflicts, ONE barrier per mg (hs publish only, verbatim).
// Wave accumulates kt-partials acc[8 colfrags] (16 rows x 128 i); B streams via
// a 4-deep rolling register window; kt-partials tree-reduced in LDS at the end.
__global__ __launch_bounds__(512, 4) void k_fused(
      const u16* __restrict__ xT,              // [4][16384][128] f16
      const u32* __restrict__ hK,              // [66][5][16384]  u32 (f16 k-pair)
      const int* __restrict__ nb,              // [9][16384]
      const u16* __restrict__ Vt,              // [128][8448]     bf16
      const float* __restrict__ bias,
      float* __restrict__ out){
  __shared__ u32 hs[2][2][5][32];                 //  2,560 B
  __shared__ int pk[KNB][32];                     //  1,152 B
  __shared__ __align__(16) float redv[3][2][16][128]; // 49,152 B (epilogue only)

  const int tid = threadIdx.x;
  const int r0  = blockIdx.x * 32;
  const int b   = r0 >> 14;
  const int l0  = r0 & (NS-1);

  if (tid < KNB*32){
    int k = tid >> 5, l = tid & 31;
    pk[k][l] = nb[k*NS + l0 + l];
  }
  WG_BARRIER();

  // ---- wave identity ----
  const int lane  = tid & 63;
  const int w     = tid >> 6;     // 0..7
  const int rf    = w >> 2;       // row-frag: rows rf*16..+16
  const int kt    = w & 3;        // K-quarter of each 128-j slab
  const int ar    = lane & 15;
  const int klane = lane >> 4;
  const int lqp   = rf*16 + ar;   // this thread's x/h row (0..31)
  const int jcp   = kt*4 + klane; // this thread's j-chunk (0..15)

  // ---- h prefetch lanes: 320 threads each own one (slab,kp,l) slot (verbatim) ----
  const bool hact = tid < 320;
  const int  hs_  = tid / 160;
  const int  hr_  = tid - hs_*160;
  const int  hkp_ = hr_ >> 5;
  const int  hl_  = hr_ & 31;
  const u32* hKp  = hK + (((size_t)(5*hs_ + hkp_)) << 14) + l0 + hl_;
  const size_t HSTR = (size_t)10 << 14;
  u32 hra = 0, hrb = 0;
  if (hact){
    u32 h0 = hKp[0];
    hra = hKp[HSTR];
    hrb = hKp[2*HSTR];
    hs[0][hs_][hkp_][hl_] = h0;
  }

  // ---- gather x rows for (lqp, jcp), pack into k-pairs (register resident) ----
  const char* xbB = (const char*)(xT + ((size_t)b << 21));
  u32 xp[5][8];
  #pragma unroll
  for (int kp = 0; kp < 4; ++kp){
    u16x8 ga = *(const u16x8*)(xbB + (((size_t)(u32)pk[2*kp  ][lqp]) << 8) + (size_t)jcp*16);
    u16x8 gb = *(const u16x8*)(xbB + (((size_t)(u32)pk[2*kp+1][lqp]) << 8) + (size_t)jcp*16);
    #pragma unroll
    for (int j = 0; j < 8; ++j) xp[kp][j] = (u32)ga[j] | ((u32)gb[j] << 16);
  }
  {
    u16x8 ga = *(const u16x8*)(xbB + (((size_t)(u32)pk[8][lqp]) << 8) + (size_t)jcp*16);
    #pragma unroll
    for (int j = 0; j < 8; ++j) xp[4][j] = (u32)ga[j];   // hi half = +0.0 f16
  }

  // ---- accumulators: kt-partial of 16 rows x 128 i ----
  floatx4 acc[8];
  #pragma unroll
  for (int cf = 0; cf < 8; ++cf) acc[cf] = (floatx4){0.f,0.f,0.f,0.f};

  // ---- B stream: step t in 0..15 per mg: s = t>>3, cf = t&7 ----
  const char*  baseK = (const char*)Vt + (size_t)ar*(QDIM*2) + kt*64 + klane*16;
  const size_t CFS   = (size_t)16*QDIM*2;   // col-frag stride
  bf16x8 bvw[4];
  #pragma unroll
  for (int t = 0; t < 4; ++t)
    bvw[t] = *(const bf16x8*)(baseK + (size_t)(t & 7)*CFS + (size_t)((t>>3))*256);

  WG_BARRIER();   // hs[0] visible

  for (int mg = 0; mg < 33; ++mg){
    const int pb = mg & 1;

    // ---- build both A fragments via packed f16 fma (r12-verified math) ----
    __half2 ac2[2][8];
    #pragma unroll
    for (int s = 0; s < 2; ++s)
      #pragma unroll
      for (int j = 0; j < 8; ++j) ac2[s][j] = __builtin_bit_cast(__half2, 0u);
    #pragma unroll
    for (int s = 0; s < 2; ++s){
      #pragma unroll
      for (int kp = 0; kp < 5; ++kp){
        __half2 hp = __builtin_bit_cast(__half2, hs[pb][s][kp][lqp]); // 16-lane bcast
        #pragma unroll
        for (int j = 0; j < 8; ++j)
          ac2[s][j] = __hfma2(__builtin_bit_cast(__half2, xp[kp][j]), hp, ac2[s][j]);
      }
    }
    bf16x8 frag[2];
    #pragma unroll
    for (int s = 0; s < 2; ++s){
      float a2[8];
      #pragma unroll
      for (int j = 0; j < 8; ++j)
        a2[j] = __low2float(ac2[s][j]) + __high2float(ac2[s][j]);
      uint4 q;
      q.x = cvtpk2(a2[0], a2[1]); q.y = cvtpk2(a2[2], a2[3]);
      q.z = cvtpk2(a2[4], a2[5]); q.w = cvtpk2(a2[6], a2[7]);
      frag[s] = __builtin_bit_cast(bf16x8, q);
    }

    // ---- MFMA stream: 16 steps (2 slabs x 8 col-frags), rolling B window ----
    #pragma unroll
    for (int t = 0; t < 16; ++t){
      const int s  = t >> 3;
      const int cf = t & 7;
      acc[cf] = __builtin_amdgcn_mfma_f32_16x16x32_bf16(frag[s], bvw[t & 3], acc[cf], 0, 0, 0);
      // reload this slot 4 steps ahead (crosses into mg+1; mg=32 tail reads
      // land in the hK region directly after Vt — valid memory, values unused)
      const int u   = t + 4;
      const int mgu = (u < 16) ? mg : (mg + 1);
      const int tu  = u & 15;
      bvw[t & 3] = *(const bf16x8*)(baseK + (size_t)(tu & 7)*CFS
                                         + (size_t)(mgu*2 + (tu >> 3))*256);
    }

    // ---- rotate h pipeline: publish mg+1, issue mg+3 (verbatim) ----
    if (hact){
      if (mg < 32) hs[pb^1][hs_][hkp_][hl_] = hra;
      hra = hrb;
      if (mg <= 29) hrb = hKp[(size_t)(mg+3)*HSTR];
    }

    WG_BARRIER();   // hs[pb^1] published; the ONLY barrier per mg
  }

  // ---- epilogue: kt-partial reduction via LDS, then bias + store ----
  if (kt != 0){
    float* rp = &redv[kt-1][rf][0][0];
    #pragma unroll
    for (int cf = 0; cf < 8; ++cf)
      #pragma unroll
      for (int j = 0; j < 4; ++j)
        rp[(klane*4 + j)*128 + cf*16 + ar] = acc[cf][j];
  }
  WG_BARRIER();
  if (kt == 0){
    float* ob = out + ((size_t)b << 21);
    const int lbase = l0 + rf*16 + klane*4;
    #pragma unroll
    for (int cf = 0; cf < 8; ++cf){
      const int i  = cf*16 + ar;
      const float bi = bias[i];
      float4 v;
      #pragma unroll
      for (int j = 0; j < 4; ++j){
        const int rr = klane*4 + j;
        float s = acc[cf][j]
                + redv[0][rf][rr][cf*16 + ar]
                + redv[1][rf][rr][cf*16 + ar]
                + redv[2][rf][rr][cf*16 + ar] + bi;
        (&v.x)[j] = s;
      }
      *(float4*)(ob + ((size_t)i << 14) + lbase) = v;
    }
  }
}

// ---------------- Naive zero-workspace fallback (correctness net) ----------------
__global__ __launch_bounds__(256) void k_naive(const float* __restrict__ x,
      const int* __restrict__ nb, const float* __restrict__ coords,
      const float* __restrict__ W1, const float* __restrict__ b1,
      const float* __restrict__ W2, const float* __restrict__ b2,
      const float* __restrict__ W3, const float* __restrict__ b3,
      const float* __restrict__ bias, float* __restrict__ out){
  __shared__ __align__(16) float hk[KNB][68];
  __shared__ int pk[KNB];
  __shared__ __align__(16) float xg[4][KNB][128];
  __shared__ __align__(16) float ul[128][66];
  int tid = threadIdx.x;
  int l = blockIdx.x;
  int lane = tid & 63, wid = tid >> 6;
  if (tid < KNB) pk[tid] = nb[tid*NS + l];
  for (int k = wid; k < KNB; k += 4){
    int pt = k*NS + l;
    float c0 = coords[2*pt], c1 = coords[2*pt+1];
    float z  = fmaf(c0, W1[lane], fmaf(c1, W1[64+lane], b1[lane]));
    float h1 = sinf(W0C*z);
    float a = b2[lane];
    for (int mp = 0; mp < 64; ++mp)
      a = fmaf(__shfl(h1, mp, 64), W2[mp*64+lane], a);
    hk[k][lane] = sinf(a);
    if (lane == 0){ hk[k][64] = 1.f; hk[k][65] = 0.f; }
  }
  __syncthreads();
  for (int idx = tid; idx < 4*KNB*128; idx += 256){
    int b = idx / (KNB*128);
    int r = idx - b*KNB*128;
    int k = r >> 7;
    int j = r & 127;
    xg[b][k][j] = x[((size_t)b*CIN + j)*NIN + pk[k]];
  }
  __syncthreads();
  for (int b = 0; b < 4; ++b){
    for (int idx = tid; idx < 128*65; idx += 256){
      int j = idx / 65, m = idx - j*65;
      float s = 0.f;
      for (int k = 0; k < KNB; ++k) s = fmaf(xg[b][k][j], hk[k][m], s);
      ul[j][m] = s;
    }
    __syncthreads();
    if (tid < 128){
      int i = tid;
      float v = bias[i];
      for (int j = 0; j < 128; ++j){
        const float* wcol = W3 + i*128 + j;
        for (int m = 0; m < 64; ++m)
          v = fmaf(ul[j][m], wcol[(size_t)m*16384], v);
        v = fmaf(ul[j][64], b3[i*128+j], v);
      }
      out[((size_t)b<<21) + ((size_t)i<<14) + l] = v;
    }
    __syncthreads();
  }
}

extern "C" void kernel_launch(void* const* d_in, const int* in_sizes, int n_in,
                              void* d_out, int out_size, void* d_ws, size_t ws_size,
                              hipStream_t stream) {
  const float* x      = (const float*)d_in[0];
  const int*   nb     = (const int*)  d_in[1];
  const float* coords = (const float*)d_in[2];
  const float* W1     = (const float*)d_in[3];
  const float* b1     = (const float*)d_in[4];
  const float* W2     = (const float*)d_in[5];
  const float* b2     = (const float*)d_in[6];
  const float* W3     = (const float*)d_in[7];
  const float* b3     = (const float*)d_in[8];
  const float* bias   = (const float*)d_in[9];
  float* out = (float*)d_out;

  const size_t VT_BYTES = (size_t)COUT*QDIM*2;        //  2,162,688
  const size_t HK_BYTES = (size_t)MCH*5*NS*4;         // 21,626,880
  const size_t XT_BYTES = (size_t)4*NIN*CIN*2;        // 16,777,216
  const size_t FIXED    = VT_BYTES + HK_BYTES + XT_BYTES;  // ~40.6 MB

  if (ws_size >= FIXED) {
    char* ws = (char*)d_ws;
    unsigned short* Vt = (unsigned short*)ws;
    u32*            hK = (u32*)(ws + VT_BYTES);
    unsigned short* xT = (unsigned short*)(ws + VT_BYTES + HK_BYTES);

    k_prep<<<PREP_K1H + PREP_KTR + PREP_K0, 1024, 0, stream>>>(
        coords, W1, b1, W2, b2, x, W3, b3, hK, xT, Vt);
    k_fused<<<(4*NS)/32, 512, 0, stream>>>(xT, hK, nb, Vt, bias, out);
  } else {
    k_naive<<<NS, 256, 0, stream>>>(x, nb, coords, W1, b1, W2, b2, W3, b3, bias, out);
  }
  (void)in_sizes; (void)n_in; (void)out_size;
}